// Round 14
// baseline (458.639 us; speedup 1.0000x reference)
//
#include <hip/hip_runtime.h>
#include <hip/hip_bf16.h>
#include <math.h>

#define NN 8192
#define FF 64
#define HH 128
#define RR 3
#define DEG 32
#define KK 32
#define EE (NN*DEG)
#define DD 131            // 2F+3
#define TEMP 0.3f
#define NEG_SLOPE 0.2f
#define EPS_LN 1e-5f
#define W_THRESH 1e-6f

typedef float v2f __attribute__((ext_vector_type(2)));
__device__ __forceinline__ float4 ld4(const float* p) { return *(const float4*)p; }
#define PKFMA(a, b, c) __builtin_elementwise_fma((a), (b), (c))
// scalar view of packed accumulator: element j (0..15) of the old float[16]
#define AIDX(a, j) a[((j)>>2)*2 + (((j)&3)>>1)][(j)&1]
#define GIDX(r, g) gaccv[r][(g)>>1][(g)&1]

// ws layout (floats):
//  [0..127]   hdr: [0]=contagion_sum [8..71]=colsum
//  [128 .. 128+EE)  edge scores
//  [tabs ..)  PA1, PA2 prefix tables
//
// NOTE (R7/R8): no second __launch_bounds__ arg — it collapses VGPR allocation
// and spills accumulators to scratch. Bound-free: ~76-120 VGPR, zero spill.
// NOTE (R10): v_pk_fma_f32 — each component is an exact IEEE FMA; per-element
// chains bit-identical to scalar.
// NOTE (R11): 512-thr/128-edge blocks regress; 256-thr/64-edge is the sweet spot.
// NOTE (R12): fusing the serial finalize into the edge-kernel tail costs ~50us;
// standalone 8192x64 finalize overlaps its serial loops across blocks (~25us).
// NOTE (R13): regime probs computed redundantly per edge block (bit-identical
// chain, WPan-region scratch) — removes one dispatch.

// ---------------- Setup kernel: blocks 0..511 = prefix tables, 512..639 = stats ----------------
__global__ __launch_bounds__(256) void setup_kernel(
    const float* __restrict__ x,
    const float* __restrict__ Ws1, const float* __restrict__ Wp,
    const float* __restrict__ Wc1, const float* __restrict__ bc1,
    const float* __restrict__ Wc2, const float* __restrict__ bc2,
    float* __restrict__ PA, float* __restrict__ hdr)
{
    __shared__ float spool[12608];
    int t = threadIdx.x;
    int bid = blockIdx.x;

    if (bid < 512) {
        // ---- partial: PA[n][c] = sum_{k<64} x[n][k] * W[k][c] (k-ascending chain) ----
        float* xs = spool;          // [32][65]
        float* wl = spool + 2080;   // [64][128]
        int which = bid & 1;
        int n0 = (bid >> 1) * 32;
        const float* base = which ? Wp : Ws1;

        for (int i = t; i < 2048; i += 256)
            xs[(i >> 6) * 65 + (i & 63)] = x[n0 * 64 + i];
        for (int it = 0; it < 8; it++) {
            int flat = (t + it * 256) * 4;
            *(float4*)&wl[flat] = ld4(&base[flat]);
        }
        __syncthreads();

        int row = t >> 3, colg = t & 7;
        float acc[16];
        #pragma unroll
        for (int j = 0; j < 16; j++) acc[j] = 0.f;
        const float* xr = &xs[row * 65];
        for (int k = 0; k < 64; k++) {
            float a = xr[k];
            const float* wr = &wl[k * 128 + colg * 16];
            #pragma unroll
            for (int jj = 0; jj < 4; jj++) {
                float4 w = ld4(wr + 4 * jj);
                acc[4*jj+0] += a * w.x; acc[4*jj+1] += a * w.y;
                acc[4*jj+2] += a * w.z; acc[4*jj+3] += a * w.w;
            }
        }
        float* outp = PA + (size_t)which * (NN * 128) + (size_t)(n0 + row) * 128 + colg * 16;
        #pragma unroll
        for (int j = 0; j < 16; j++) outp[j] = acc[j];
    } else {
        // ---- stats: column sums of x + contagion level ----
        float* xs = spool;          // [64][65]
        float* wl = spool + 4160;   // [64][128]
        float* cs = spool + 12352;  // [4][64]
        int n0 = (bid - 512) * 64;

        for (int i = 0; i < 16; i++) {
            int flat = t + i * 256;
            int r = flat >> 6, c = flat & 63;
            xs[r * 65 + c] = x[(n0 + r) * 64 + c];
        }
        for (int i = 0; i < 8; i++) {
            int flat = (t + i * 256) * 4;
            *(float4*)&wl[flat] = ld4(&Wc1[flat]);
        }
        __syncthreads();

        {
            int col = t & 63, g = t >> 6;
            float ps = 0.f;
            for (int r = g * 16; r < g * 16 + 16; r++) ps += xs[r * 65 + col];
            cs[g * 64 + col] = ps;
        }
        __syncthreads();
        if (t < 64) {
            float v = cs[t] + cs[64 + t] + cs[128 + t] + cs[192 + t];
            atomicAdd(&hdr[8 + t], v);
        }

        int r = t >> 2, q = t & 3;
        float accl = 0.f;
        for (int hh = 0; hh < 32; hh++) {
            int h = hh * 4 + q;
            float s = bc1[h];
            for (int i = 0; i < 64; i++) s += xs[r * 65 + i] * wl[i * 128 + h];
            accl += fmaxf(s, 0.f) * Wc2[h];
        }
        accl += __shfl_xor(accl, 1);
        accl += __shfl_xor(accl, 2);
        if (q == 0) {
            float lvl = 1.f / (1.f + expf(-(accl + bc2[0])));
            atomicAdd(&hdr[0], lvl);
        }
    }
}

// ---------------- Fused edge kernel: 256 thr / 64 edges, pk-fp32, inline regime ----------------
// LDS pool (floats):
//   prologue: EIB staging @0, regime scratch in WPan region (gsl@4864, t1@4928)
//   phase A: EIB[64][76] @0 (4864), WPan[2][12][128] @4864 (3072)  -> 7936
//   phase B: ehTh[64][68] @0 (4352), WgPan[3][16][64] @4352 (3072) -> 7424
//   phase C: Gbuf[64][68] @0 (4352)
//   persistent: rawS @7936 (64); pool = 8000 fl = 32000 B (+hdrS 16 B)
#define EIB_S 76
__global__ __launch_bounds__(256) void edge_fused_kernel(
    const int* __restrict__ tgt_idx, const float* __restrict__ edge_attr,
    const float* __restrict__ x,
    const float* __restrict__ Ws1, const float* __restrict__ bs1,
    const float* __restrict__ ln_g, const float* __restrict__ ln_b,
    const float* __restrict__ Ws2, const float* __restrict__ bs2,
    const float* __restrict__ Wp, const float* __restrict__ bp,
    const float* __restrict__ Wg1, const float* __restrict__ bg1,
    const float* __restrict__ Wg2, const float* __restrict__ bg2,
    const float* __restrict__ Wr1, const float* __restrict__ br1,
    const float* __restrict__ Wr2, const float* __restrict__ br2,
    const float* __restrict__ PA1, const float* __restrict__ PA2,
    const float* __restrict__ hdr, float* __restrict__ scores)
{
    __shared__ float pool[8000];
    __shared__ float hdrS[4];       // [0..2]=regime_probs, [3]=amp
    float* EIB   = pool;            // [64][76]
    float* WPan  = pool + 4864;     // [2][12][128]
    float* gslL  = pool + 4864;     // regime scratch (dead before WPan staging)
    float* t1L   = pool + 4928;     // [128]
    float* ehTh  = pool;            // [64 k-local][68]
    float* WgPan = pool + 4352;     // [3][16][64]
    float* Gbuf  = pool;            // [64 m][68]
    float* rawS  = pool + 7936;     // [64]

    int t = threadIdx.x;
    int e0 = blockIdx.x * 64;

    // ---- stage shifted edge input: local col ii <-> original k = 64+ii ----
    {
        int r = t >> 2, q = t & 3;
        int ge = e0 + r;
        int tg = tgt_idx[ge];
        #pragma unroll
        for (int i = 0; i < 4; i++) {
            int col = q * 16 + 4 * i;
            *(float4*)&EIB[r * EIB_S + col] = ld4(&x[tg * 64 + col]);
        }
        if (q == 0) {
            float4 v;
            v.x = edge_attr[(size_t)ge * 3 + 0];
            v.y = edge_attr[(size_t)ge * 3 + 1];
            v.z = edge_attr[(size_t)ge * 3 + 2];
            v.w = 0.f;
            *(float4*)&EIB[r * EIB_S + 64] = v;
        } else if (q == 1) {
            *(float4*)&EIB[r * EIB_S + 68] = make_float4(0.f, 0.f, 0.f, 0.f);
        } else if (q == 2) {
            *(float4*)&EIB[r * EIB_S + 72] = make_float4(0.f, 0.f, 0.f, 0.f);
        }
    }

    // ---- inline regime (bit-identical to the old regime_kernel chain) ----
    if (t < 64) gslL[t] = hdr[8 + t] * (1.f / (float)NN);
    __syncthreads();
    if (t < 128) {
        float a = br1[t];
        for (int i = 0; i < 64; i++) a += gslL[i] * Wr1[i * 128 + t];
        t1L[t] = fmaxf(a, 0.f);
    }
    __syncthreads();
    if (t < 3) {
        float v = br2[t];
        for (int h = 0; h < 128; h++) v += t1L[h] * Wr2[h * 3 + t];
        gslL[32 + t] = v;
    }
    __syncthreads();
    if (t == 0) {
        float v0 = gslL[32], v1 = gslL[33], v2 = gslL[34];
        float m = fmaxf(v0, fmaxf(v1, v2));
        float e0v = expf(v0 - m), e1v = expf(v1 - m), e2v = expf(v2 - m);
        float inv = 1.f / (e0v + e1v + e2v);
        hdrS[0] = e0v * inv; hdrS[1] = e1v * inv; hdrS[2] = e2v * inv;
        hdrS[3] = 1.f + 0.5f * (hdr[0] * (1.f / (float)NN));
    }
    // (GEMM loop's first __syncthreads makes hdrS visible and frees gslL/t1L)

    int tcol = t & 7, trow = t >> 3;   // scalar col j: tcol*4 + (j>>2)*32 + (j&3); rows 2*trow,2*trow+1
    const float* EIr0 = &EIB[(2 * trow) * EIB_S];
    const float* EIr1 = EIr0 + EIB_S;
    int src = (e0 + 2 * trow) >> 5;

    v2f accs0[8], accs1[8], accp0[8], accp1[8];

    // ---- init accumulators from prefix tables (exact chain state after k=63) ----
    {
        const float* p1 = &PA1[(size_t)src * 128 + tcol * 4];
        const float* p2 = &PA2[(size_t)src * 128 + tcol * 4];
        #pragma unroll
        for (int jj = 0; jj < 4; jj++) {
            float4 v;
            v = ld4(p1 + jj * 32);
            v2f lo1 = { v.x, v.y }, hi1 = { v.z, v.w };
            accs0[jj*2] = lo1; accs0[jj*2+1] = hi1;
            accs1[jj*2] = lo1; accs1[jj*2+1] = hi1;
            v = ld4(p2 + jj * 32);
            v2f lo2 = { v.x, v.y }, hi2 = { v.z, v.w };
            accp0[jj*2] = lo2; accp0[jj*2+1] = hi2;
            accp1[jj*2] = lo2; accp1[jj*2+1] = hi2;
        }
    }

    // ---- fused dual-GEMM k-loop: 6 panels x 12 rows (original k = 64..135) ----
    for (int p = 0; p < 6; p++) {
        __syncthreads();
        #pragma unroll
        for (int i = 0; i < 3; i++) {
            int fid = i * 256 + t;             // 0..767 float4s
            int mat = (fid >= 384) ? 1 : 0;
            int loc = fid - mat * 384;
            int pr = loc >> 5;                 // 0..11
            int pc = (loc & 31) * 4;
            int wrow = 64 + p * 12 + pr;
            const float* Wsrc = mat ? Wp : Ws1;
            float4 w = (wrow < 131) ? ld4(&Wsrc[wrow * 128 + pc])
                                    : make_float4(0.f, 0.f, 0.f, 0.f);
            *(float4*)&WPan[mat * 1536 + pr * 128 + pc] = w;
        }
        __syncthreads();
        for (int kk = 0; kk < 12; kk++) {
            int k = p * 12 + kk;
            float a0 = EIr0[k];
            float a1 = EIr1[k];
            v2f a0v = { a0, a0 }, a1v = { a1, a1 };
            const float* ws = &WPan[kk * 128 + tcol * 4];
            const float* wq = ws + 1536;
            #pragma unroll
            for (int jj = 0; jj < 4; jj++) {
                float4 w1 = ld4(ws + jj * 32);
                v2f w1a = { w1.x, w1.y }, w1b = { w1.z, w1.w };
                accs0[jj*2]   = PKFMA(a0v, w1a, accs0[jj*2]);
                accs0[jj*2+1] = PKFMA(a0v, w1b, accs0[jj*2+1]);
                accs1[jj*2]   = PKFMA(a1v, w1a, accs1[jj*2]);
                accs1[jj*2+1] = PKFMA(a1v, w1b, accs1[jj*2+1]);
                float4 w2 = ld4(wq + jj * 32);
                v2f w2a = { w2.x, w2.y }, w2b = { w2.z, w2.w };
                accp0[jj*2]   = PKFMA(a0v, w2a, accp0[jj*2]);
                accp0[jj*2+1] = PKFMA(a0v, w2b, accp0[jj*2+1]);
                accp1[jj*2]   = PKFMA(a1v, w2a, accp1[jj*2]);
                accp1[jj*2+1] = PKFMA(a1v, w2b, accp1[jj*2+1]);
            }
        }
    }

    // ---- +bias, LayerNorm, LeakyReLU, dot Ws2 (verbatim scalar chains) ----
    {
        float s0 = 0.f, ss0 = 0.f, s1 = 0.f, ss1 = 0.f;
        #pragma unroll
        for (int j = 0; j < 16; j++) {
            int col = tcol * 4 + (j >> 2) * 32 + (j & 3);
            float b = bs1[col];
            float u0 = AIDX(accs0, j) + b;  AIDX(accs0, j) = u0;
            float u1 = AIDX(accs1, j) + b;  AIDX(accs1, j) = u1;
            s0 += u0; ss0 += u0 * u0;
            s1 += u1; ss1 += u1 * u1;
        }
        #pragma unroll
        for (int m = 1; m < 8; m <<= 1) {
            s0 += __shfl_xor(s0, m);  ss0 += __shfl_xor(ss0, m);
            s1 += __shfl_xor(s1, m);  ss1 += __shfl_xor(ss1, m);
        }
        float mu0 = s0 * (1.f / 128.f), mu1 = s1 * (1.f / 128.f);
        float var0 = ss0 * (1.f / 128.f) - mu0 * mu0;
        float var1 = ss1 * (1.f / 128.f) - mu1 * mu1;
        float inv0 = 1.f / sqrtf(var0 + EPS_LN);
        float inv1 = 1.f / sqrtf(var1 + EPS_LN);
        float d0 = 0.f, d1 = 0.f;
        #pragma unroll
        for (int j = 0; j < 16; j++) {
            int col = tcol * 4 + (j >> 2) * 32 + (j & 3);
            float g = ln_g[col], bb = ln_b[col], w2 = Ws2[col];
            float y0 = (AIDX(accs0, j) - mu0) * inv0 * g + bb;
            float y1 = (AIDX(accs1, j) - mu1) * inv1 * g + bb;
            y0 = (y0 >= 0.f) ? y0 : NEG_SLOPE * y0;
            y1 = (y1 >= 0.f) ? y1 : NEG_SLOPE * y1;
            d0 += y0 * w2; d1 += y1 * w2;
        }
        #pragma unroll
        for (int m = 1; m < 8; m <<= 1) {
            d0 += __shfl_xor(d0, m); d1 += __shfl_xor(d1, m);
        }
        if (tcol == 0) {
            rawS[2 * trow]     = d0 + bs2[0];
            rawS[2 * trow + 1] = d1 + bs2[0];
        }
    }

    // ================= gating: two 64-k halves of ehT, packed gacc persists =================
    int gtr = t >> 4, gtc = t & 15;            // edges 4*gtr+i ; m 4*gtc+j
    int grow = t >> 2, gq = t & 3;             // p-phase mapping (R1 chain)

    v2f gaccv[3][8];
    #pragma unroll
    for (int rr = 0; rr < 3; rr++)
        #pragma unroll
        for (int j = 0; j < 8; j++) gaccv[rr][j] = (v2f){ 0.f, 0.f };

    for (int hf = 0; hf < 2; hf++) {
        __syncthreads();                       // EIB/WPan (hf=0) or prior ehTh reads done
        #pragma unroll
        for (int j2 = 0; j2 < 8; j2++) {
            int j = hf * 8 + j2;
            int col = tcol * 4 + (j >> 2) * 32 + (j & 3);
            int lc = col - hf * 64;            // 0..63
            float b = bp[col];
            ehTh[lc * 68 + 2 * trow]     = fmaxf(AIDX(accp0, j) + b, 0.f);
            ehTh[lc * 68 + 2 * trow + 1] = fmaxf(AIDX(accp1, j) + b, 0.f);
        }
        for (int p = 0; p < 4; p++) {
            __syncthreads();                   // ehTh writes visible (p==0) / prior panel reads done
            #pragma unroll
            for (int i = 0; i < 3; i++) {
                int fid = i * 256 + t;         // 0..767 float4s
                int rr = fid >> 8;
                int loc = fid & 255;
                int pr = loc >> 4;             // 0..15
                int pc = (loc & 15) * 4;
                *(float4*)&WgPan[rr * 1024 + pr * 64 + pc] =
                    ld4(&Wg1[(size_t)(rr * 128 + hf * 64 + p * 16 + pr) * 64 + pc]);
            }
            __syncthreads();
            for (int kk = 0; kk < 16; kk++) {
                float4 av = ld4(&ehTh[(p * 16 + kk) * 68 + 4 * gtr]);
                v2f ax = { av.x, av.x }, ay = { av.y, av.y };
                v2f az = { av.z, av.z }, aw = { av.w, av.w };
                #pragma unroll
                for (int rr = 0; rr < 3; rr++) {
                    float4 bv = ld4(&WgPan[rr * 1024 + kk * 64 + 4 * gtc]);
                    v2f bva = { bv.x, bv.y }, bvb = { bv.z, bv.w };
                    gaccv[rr][0] = PKFMA(ax, bva, gaccv[rr][0]);
                    gaccv[rr][1] = PKFMA(ax, bvb, gaccv[rr][1]);
                    gaccv[rr][2] = PKFMA(ay, bva, gaccv[rr][2]);
                    gaccv[rr][3] = PKFMA(ay, bvb, gaccv[rr][3]);
                    gaccv[rr][4] = PKFMA(az, bva, gaccv[rr][4]);
                    gaccv[rr][5] = PKFMA(az, bvb, gaccv[rr][5]);
                    gaccv[rr][6] = PKFMA(aw, bva, gaccv[rr][6]);
                    gaccv[rr][7] = PKFMA(aw, bvb, gaccv[rr][7]);
                }
            }
        }
    }

    // ---- Gbuf + p-phase per regime (R1 lane mapping / add order) ----
    float gc = 0.f;
    for (int rr = 0; rr < 3; rr++) {
        __syncthreads();                       // ehTh k-loop reads (rr==0) / prior p-phase reads done
        #pragma unroll
        for (int j = 0; j < 4; j++) {
            float b = bg1[rr * 64 + 4 * gtc + j];
            float4 g;
            g.x = fmaxf(GIDX(rr, 0  + j) + b, 0.f);
            g.y = fmaxf(GIDX(rr, 4  + j) + b, 0.f);
            g.z = fmaxf(GIDX(rr, 8  + j) + b, 0.f);
            g.w = fmaxf(GIDX(rr, 12 + j) + b, 0.f);
            *(float4*)&Gbuf[(4 * gtc + j) * 68 + 4 * gtr] = g;
        }
        __syncthreads();
        float pacc = 0.f;
        #pragma unroll
        for (int j = 0; j < 16; j++) {
            int m = gq * 4 + (j >> 2) * 16 + (j & 3);
            pacc += Gbuf[m * 68 + grow] * Wg2[rr * 64 + m];
        }
        pacc += __shfl_xor(pacc, 1);
        pacc += __shfl_xor(pacc, 2);
        float gate = 1.f / (1.f + expf(-(pacc + bg2[rr])));
        gc += gate * hdrS[rr];
    }
    if (gq == 0) scores[e0 + grow] = rawS[grow] * gc * hdrS[3];
}

// ---------------- Kernel D: per-row dedup + softmax + stable top-k ----------------
__global__ __launch_bounds__(64) void finalize_kernel(
    const int* __restrict__ tgt_idx, const float* __restrict__ scores,
    float* __restrict__ out_w, float* __restrict__ out_i)
{
    __shared__ int   tl[32];
    __shared__ float pl[32];
    int j = threadIdx.x;
    int row = blockIdx.x;
    bool lane_active = (j < 32);
    int   tg = 0;
    float s  = -INFINITY;
    if (lane_active) {
        tg = tgt_idx[row * 32 + j];
        s  = scores[row * 32 + j];
        tl[j] = tg;
    }
    __syncthreads();

    bool alive = false;
    if (lane_active) {
        alive = true;
        for (int j2 = j + 1; j2 < 32; j2++)
            if (tl[j2] == tg) { alive = false; break; }
    }
    float z = (lane_active && alive) ? s * (1.f / TEMP) : -INFINITY;
    float m = z;
    #pragma unroll
    for (int mm = 1; mm < 64; mm <<= 1) m = fmaxf(m, __shfl_xor(m, mm));
    float p = (lane_active && alive) ? expf(z - m) : 0.f;
    float sum = p;
    #pragma unroll
    for (int mm = 1; mm < 64; mm <<= 1) sum += __shfl_xor(sum, mm);
    p = p / sum;
    if (lane_active) pl[j] = alive ? p : -1.f;
    __syncthreads();

    int rank = 0, dcount = 0;
    for (int j2 = 0; j2 < 32; j2++) {
        float pj = pl[j2];
        if (pj >= 0.f) {
            dcount++;
            if (lane_active && alive) {
                if (pj > p || (pj == p && tl[j2] < tg)) rank++;
            }
        }
    }
    if (lane_active && alive) {
        out_w[row * 32 + rank] = (p > W_THRESH) ? p : 0.f;
        out_i[row * 32 + rank] = (float)tg;
    }
    if (j == 0) {
        int c = 0;
        for (int slot = dcount; slot < 32; slot++) {
            for (;;) {
                bool found = false;
                for (int q = 0; q < 32; q++) if (tl[q] == c) { found = true; break; }
                if (!found) break;
                c++;
            }
            out_w[row * 32 + slot] = 0.f;
            out_i[row * 32 + slot] = (float)c;
            c++;
        }
    }
}

extern "C" void kernel_launch(void* const* d_in, const int* in_sizes, int n_in,
                              void* d_out, int out_size, void* d_ws, size_t ws_size,
                              hipStream_t stream)
{
    const float* x          = (const float*)d_in[0];
    const int*   edge_index = (const int*)  d_in[1];
    const float* edge_attr  = (const float*)d_in[2];
    const float* Ws1 = (const float*)d_in[3];
    const float* bs1 = (const float*)d_in[4];
    const float* ln_g = (const float*)d_in[5];
    const float* ln_b = (const float*)d_in[6];
    const float* Ws2 = (const float*)d_in[7];
    const float* bs2 = (const float*)d_in[8];
    const float* Wp  = (const float*)d_in[9];
    const float* bp  = (const float*)d_in[10];
    const float* Wr1 = (const float*)d_in[11];
    const float* br1 = (const float*)d_in[12];
    const float* Wr2 = (const float*)d_in[13];
    const float* br2 = (const float*)d_in[14];
    const float* Wg1 = (const float*)d_in[15];
    const float* bg1 = (const float*)d_in[16];
    const float* Wg2 = (const float*)d_in[17];
    const float* bg2 = (const float*)d_in[18];
    const float* Wc1 = (const float*)d_in[19];
    const float* bc1 = (const float*)d_in[20];
    const float* Wc2 = (const float*)d_in[21];
    const float* bc2 = (const float*)d_in[22];

    float* hdr    = (float*)d_ws;
    float* scores = hdr + 128;
    float* tabs   = scores + EE;            // PA1, PA2
    const int* tgt = edge_index + EE;       // row 1 of edge_index

    hipMemsetAsync(d_ws, 0, 512, stream);
    setup_kernel<<<640, 256, 0, stream>>>(x, Ws1, Wp, Wc1, bc1, Wc2, bc2, tabs, hdr);
    edge_fused_kernel<<<EE / 64, 256, 0, stream>>>(
        tgt, edge_attr, x, Ws1, bs1, ln_g, ln_b, Ws2, bs2, Wp, bp,
        Wg1, bg1, Wg2, bg2, Wr1, br1, Wr2, br2,
        tabs, tabs + (size_t)NN * 128, hdr, scores);
    finalize_kernel<<<NN, 64, 0, stream>>>(
        tgt, scores, (float*)d_out, (float*)d_out + NN * KK);
}

// Round 15
// 445.708 us; speedup vs baseline: 1.0290x; 1.0290x over previous
//
#include <hip/hip_runtime.h>
#include <hip/hip_bf16.h>
#include <math.h>

#define NN 8192
#define FF 64
#define HH 128
#define RR 3
#define DEG 32
#define KK 32
#define EE (NN*DEG)
#define DD 131            // 2F+3
#define TEMP 0.3f
#define NEG_SLOPE 0.2f
#define EPS_LN 1e-5f
#define W_THRESH 1e-6f

typedef float v2f __attribute__((ext_vector_type(2)));
__device__ __forceinline__ float4 ld4(const float* p) { return *(const float4*)p; }
#define PKFMA(a, b, c) __builtin_elementwise_fma((a), (b), (c))
// scalar view of packed accumulator: element j (0..15) of the old float[16]
#define AIDX(a, j) a[((j)>>2)*2 + (((j)&3)>>1)][(j)&1]
#define GIDX(r, g) gaccv[r][(g)>>1][(g)&1]

// ws layout (floats):
//  [0..127]   hdr: [0]=contagion_sum [1..3]=regime_probs [4]=amp [8..71]=colsum
//  [128 .. 128+EE)  edge scores
//  [tabs ..)  PA1, PA2 prefix tables
//
// Session-converged configuration (best measured: 456.2 us, R13 bench):
// NOTE (R7/R8): no second __launch_bounds__ arg — it collapses VGPR allocation
// and spills accumulators to scratch. Bound-free: ~76-120 VGPR, zero spill.
// NOTE (R10): v_pk_fma_f32 — each component is an exact IEEE FMA; per-element
// chains bit-identical to scalar.
// NOTE (R11): 512-thr/128-edge blocks regress; 256-thr/64-edge is the sweet spot.
// NOTE (R12): fusing the serial finalize into the edge-kernel tail costs ~50us;
// standalone 8192x64 finalize overlaps its serial loops across blocks (~25us).
// NOTE (R14): inlining regime into the edge prologue costs ~15us (serial
// prologue on every block's critical path) — keep it as a standalone dispatch.

// ---------------- Setup kernel: blocks 0..511 = prefix tables, 512..639 = stats ----------------
__global__ __launch_bounds__(256) void setup_kernel(
    const float* __restrict__ x,
    const float* __restrict__ Ws1, const float* __restrict__ Wp,
    const float* __restrict__ Wc1, const float* __restrict__ bc1,
    const float* __restrict__ Wc2, const float* __restrict__ bc2,
    float* __restrict__ PA, float* __restrict__ hdr)
{
    __shared__ float spool[12608];
    int t = threadIdx.x;
    int bid = blockIdx.x;

    if (bid < 512) {
        // ---- partial: PA[n][c] = sum_{k<64} x[n][k] * W[k][c] (k-ascending chain) ----
        float* xs = spool;          // [32][65]
        float* wl = spool + 2080;   // [64][128]
        int which = bid & 1;
        int n0 = (bid >> 1) * 32;
        const float* base = which ? Wp : Ws1;

        for (int i = t; i < 2048; i += 256)
            xs[(i >> 6) * 65 + (i & 63)] = x[n0 * 64 + i];
        for (int it = 0; it < 8; it++) {
            int flat = (t + it * 256) * 4;
            *(float4*)&wl[flat] = ld4(&base[flat]);
        }
        __syncthreads();

        int row = t >> 3, colg = t & 7;
        float acc[16];
        #pragma unroll
        for (int j = 0; j < 16; j++) acc[j] = 0.f;
        const float* xr = &xs[row * 65];
        for (int k = 0; k < 64; k++) {
            float a = xr[k];
            const float* wr = &wl[k * 128 + colg * 16];
            #pragma unroll
            for (int jj = 0; jj < 4; jj++) {
                float4 w = ld4(wr + 4 * jj);
                acc[4*jj+0] += a * w.x; acc[4*jj+1] += a * w.y;
                acc[4*jj+2] += a * w.z; acc[4*jj+3] += a * w.w;
            }
        }
        float* outp = PA + (size_t)which * (NN * 128) + (size_t)(n0 + row) * 128 + colg * 16;
        #pragma unroll
        for (int j = 0; j < 16; j++) outp[j] = acc[j];
    } else {
        // ---- stats: column sums of x + contagion level ----
        float* xs = spool;          // [64][65]
        float* wl = spool + 4160;   // [64][128]
        float* cs = spool + 12352;  // [4][64]
        int n0 = (bid - 512) * 64;

        for (int i = 0; i < 16; i++) {
            int flat = t + i * 256;
            int r = flat >> 6, c = flat & 63;
            xs[r * 65 + c] = x[(n0 + r) * 64 + c];
        }
        for (int i = 0; i < 8; i++) {
            int flat = (t + i * 256) * 4;
            *(float4*)&wl[flat] = ld4(&Wc1[flat]);
        }
        __syncthreads();

        {
            int col = t & 63, g = t >> 6;
            float ps = 0.f;
            for (int r = g * 16; r < g * 16 + 16; r++) ps += xs[r * 65 + col];
            cs[g * 64 + col] = ps;
        }
        __syncthreads();
        if (t < 64) {
            float v = cs[t] + cs[64 + t] + cs[128 + t] + cs[192 + t];
            atomicAdd(&hdr[8 + t], v);
        }

        int r = t >> 2, q = t & 3;
        float accl = 0.f;
        for (int hh = 0; hh < 32; hh++) {
            int h = hh * 4 + q;
            float s = bc1[h];
            for (int i = 0; i < 64; i++) s += xs[r * 65 + i] * wl[i * 128 + h];
            accl += fmaxf(s, 0.f) * Wc2[h];
        }
        accl += __shfl_xor(accl, 1);
        accl += __shfl_xor(accl, 2);
        if (q == 0) {
            float lvl = 1.f / (1.f + expf(-(accl + bc2[0])));
            atomicAdd(&hdr[0], lvl);
        }
    }
}

// ---------------- Kernel B: regime probs + amp ----------------
__global__ __launch_bounds__(128) void regime_kernel(
    const float* __restrict__ Wr1, const float* __restrict__ br1,
    const float* __restrict__ Wr2, const float* __restrict__ br2,
    float* __restrict__ hdr)
{
    __shared__ float gsl[64];
    __shared__ float t1[128];
    int t = threadIdx.x;
    if (t < 64) gsl[t] = hdr[8 + t] * (1.f / (float)NN);
    __syncthreads();
    float a = br1[t];
    for (int i = 0; i < 64; i++) a += gsl[i] * Wr1[i * 128 + t];
    t1[t] = fmaxf(a, 0.f);
    __syncthreads();
    if (t < 3) {
        float v = br2[t];
        for (int h = 0; h < 128; h++) v += t1[h] * Wr2[h * 3 + t];
        gsl[32 + t] = v;
    }
    __syncthreads();
    if (t == 0) {
        float v0 = gsl[32], v1 = gsl[33], v2 = gsl[34];
        float m = fmaxf(v0, fmaxf(v1, v2));
        float e0 = expf(v0 - m), e1 = expf(v1 - m), e2 = expf(v2 - m);
        float inv = 1.f / (e0 + e1 + e2);
        hdr[1] = e0 * inv; hdr[2] = e1 * inv; hdr[3] = e2 * inv;
        hdr[4] = 1.f + 0.5f * (hdr[0] * (1.f / (float)NN));
    }
}

// ---------------- Fused edge kernel: R10-proven (335 us). 256 thr / 64 edges ----------------
// LDS pool (floats):
//   phase A: EIB[64][76] @0 (4864), WPan[2][12][128] @4864 (3072)  -> 7936
//   phase B: ehTh[64][68] @0 (4352), WgPan[3][16][64] @4352 (3072) -> 7424
//   phase C: Gbuf[64][68] @0 (4352)
//   persistent: rawS @7936 (64); pool = 8000 fl = 32000 B
#define EIB_S 76
__global__ __launch_bounds__(256) void edge_fused_kernel(
    const int* __restrict__ tgt_idx, const float* __restrict__ edge_attr,
    const float* __restrict__ x,
    const float* __restrict__ Ws1, const float* __restrict__ bs1,
    const float* __restrict__ ln_g, const float* __restrict__ ln_b,
    const float* __restrict__ Ws2, const float* __restrict__ bs2,
    const float* __restrict__ Wp, const float* __restrict__ bp,
    const float* __restrict__ Wg1, const float* __restrict__ bg1,
    const float* __restrict__ Wg2, const float* __restrict__ bg2,
    const float* __restrict__ PA1, const float* __restrict__ PA2,
    const float* __restrict__ hdr, float* __restrict__ scores)
{
    __shared__ float pool[8000];
    float* EIB   = pool;            // [64][76]
    float* WPan  = pool + 4864;     // [2][12][128]
    float* ehTh  = pool;            // [64 k-local][68]
    float* WgPan = pool + 4352;     // [3][16][64]
    float* Gbuf  = pool;            // [64 m][68]
    float* rawS  = pool + 7936;     // [64]

    int t = threadIdx.x;
    int e0 = blockIdx.x * 64;

    // ---- stage shifted edge input: local col ii <-> original k = 64+ii ----
    {
        int r = t >> 2, q = t & 3;
        int ge = e0 + r;
        int tg = tgt_idx[ge];
        #pragma unroll
        for (int i = 0; i < 4; i++) {
            int col = q * 16 + 4 * i;
            *(float4*)&EIB[r * EIB_S + col] = ld4(&x[tg * 64 + col]);
        }
        if (q == 0) {
            float4 v;
            v.x = edge_attr[(size_t)ge * 3 + 0];
            v.y = edge_attr[(size_t)ge * 3 + 1];
            v.z = edge_attr[(size_t)ge * 3 + 2];
            v.w = 0.f;
            *(float4*)&EIB[r * EIB_S + 64] = v;
        } else if (q == 1) {
            *(float4*)&EIB[r * EIB_S + 68] = make_float4(0.f, 0.f, 0.f, 0.f);
        } else if (q == 2) {
            *(float4*)&EIB[r * EIB_S + 72] = make_float4(0.f, 0.f, 0.f, 0.f);
        }
    }

    int tcol = t & 7, trow = t >> 3;   // scalar col j: tcol*4 + (j>>2)*32 + (j&3); rows 2*trow,2*trow+1
    const float* EIr0 = &EIB[(2 * trow) * EIB_S];
    const float* EIr1 = EIr0 + EIB_S;
    int src = (e0 + 2 * trow) >> 5;

    v2f accs0[8], accs1[8], accp0[8], accp1[8];

    // ---- init accumulators from prefix tables (exact chain state after k=63) ----
    {
        const float* p1 = &PA1[(size_t)src * 128 + tcol * 4];
        const float* p2 = &PA2[(size_t)src * 128 + tcol * 4];
        #pragma unroll
        for (int jj = 0; jj < 4; jj++) {
            float4 v;
            v = ld4(p1 + jj * 32);
            v2f lo1 = { v.x, v.y }, hi1 = { v.z, v.w };
            accs0[jj*2] = lo1; accs0[jj*2+1] = hi1;
            accs1[jj*2] = lo1; accs1[jj*2+1] = hi1;
            v = ld4(p2 + jj * 32);
            v2f lo2 = { v.x, v.y }, hi2 = { v.z, v.w };
            accp0[jj*2] = lo2; accp0[jj*2+1] = hi2;
            accp1[jj*2] = lo2; accp1[jj*2+1] = hi2;
        }
    }

    // ---- fused dual-GEMM k-loop: 6 panels x 12 rows (original k = 64..135) ----
    for (int p = 0; p < 6; p++) {
        __syncthreads();
        #pragma unroll
        for (int i = 0; i < 3; i++) {
            int fid = i * 256 + t;             // 0..767 float4s
            int mat = (fid >= 384) ? 1 : 0;
            int loc = fid - mat * 384;
            int pr = loc >> 5;                 // 0..11
            int pc = (loc & 31) * 4;
            int wrow = 64 + p * 12 + pr;
            const float* Wsrc = mat ? Wp : Ws1;
            float4 w = (wrow < 131) ? ld4(&Wsrc[wrow * 128 + pc])
                                    : make_float4(0.f, 0.f, 0.f, 0.f);
            *(float4*)&WPan[mat * 1536 + pr * 128 + pc] = w;
        }
        __syncthreads();
        for (int kk = 0; kk < 12; kk++) {
            int k = p * 12 + kk;
            float a0 = EIr0[k];
            float a1 = EIr1[k];
            v2f a0v = { a0, a0 }, a1v = { a1, a1 };
            const float* ws = &WPan[kk * 128 + tcol * 4];
            const float* wq = ws + 1536;
            #pragma unroll
            for (int jj = 0; jj < 4; jj++) {
                float4 w1 = ld4(ws + jj * 32);
                v2f w1a = { w1.x, w1.y }, w1b = { w1.z, w1.w };
                accs0[jj*2]   = PKFMA(a0v, w1a, accs0[jj*2]);
                accs0[jj*2+1] = PKFMA(a0v, w1b, accs0[jj*2+1]);
                accs1[jj*2]   = PKFMA(a1v, w1a, accs1[jj*2]);
                accs1[jj*2+1] = PKFMA(a1v, w1b, accs1[jj*2+1]);
                float4 w2 = ld4(wq + jj * 32);
                v2f w2a = { w2.x, w2.y }, w2b = { w2.z, w2.w };
                accp0[jj*2]   = PKFMA(a0v, w2a, accp0[jj*2]);
                accp0[jj*2+1] = PKFMA(a0v, w2b, accp0[jj*2+1]);
                accp1[jj*2]   = PKFMA(a1v, w2a, accp1[jj*2]);
                accp1[jj*2+1] = PKFMA(a1v, w2b, accp1[jj*2+1]);
            }
        }
    }

    // ---- +bias, LayerNorm, LeakyReLU, dot Ws2 (verbatim scalar chains) ----
    {
        float s0 = 0.f, ss0 = 0.f, s1 = 0.f, ss1 = 0.f;
        #pragma unroll
        for (int j = 0; j < 16; j++) {
            int col = tcol * 4 + (j >> 2) * 32 + (j & 3);
            float b = bs1[col];
            float u0 = AIDX(accs0, j) + b;  AIDX(accs0, j) = u0;
            float u1 = AIDX(accs1, j) + b;  AIDX(accs1, j) = u1;
            s0 += u0; ss0 += u0 * u0;
            s1 += u1; ss1 += u1 * u1;
        }
        #pragma unroll
        for (int m = 1; m < 8; m <<= 1) {
            s0 += __shfl_xor(s0, m);  ss0 += __shfl_xor(ss0, m);
            s1 += __shfl_xor(s1, m);  ss1 += __shfl_xor(ss1, m);
        }
        float mu0 = s0 * (1.f / 128.f), mu1 = s1 * (1.f / 128.f);
        float var0 = ss0 * (1.f / 128.f) - mu0 * mu0;
        float var1 = ss1 * (1.f / 128.f) - mu1 * mu1;
        float inv0 = 1.f / sqrtf(var0 + EPS_LN);
        float inv1 = 1.f / sqrtf(var1 + EPS_LN);
        float d0 = 0.f, d1 = 0.f;
        #pragma unroll
        for (int j = 0; j < 16; j++) {
            int col = tcol * 4 + (j >> 2) * 32 + (j & 3);
            float g = ln_g[col], bb = ln_b[col], w2 = Ws2[col];
            float y0 = (AIDX(accs0, j) - mu0) * inv0 * g + bb;
            float y1 = (AIDX(accs1, j) - mu1) * inv1 * g + bb;
            y0 = (y0 >= 0.f) ? y0 : NEG_SLOPE * y0;
            y1 = (y1 >= 0.f) ? y1 : NEG_SLOPE * y1;
            d0 += y0 * w2; d1 += y1 * w2;
        }
        #pragma unroll
        for (int m = 1; m < 8; m <<= 1) {
            d0 += __shfl_xor(d0, m); d1 += __shfl_xor(d1, m);
        }
        if (tcol == 0) {
            rawS[2 * trow]     = d0 + bs2[0];
            rawS[2 * trow + 1] = d1 + bs2[0];
        }
    }

    // ================= gating: two 64-k halves of ehT, packed gacc persists =================
    int gtr = t >> 4, gtc = t & 15;            // edges 4*gtr+i ; m 4*gtc+j
    int grow = t >> 2, gq = t & 3;             // p-phase mapping (R1 chain)

    v2f gaccv[3][8];
    #pragma unroll
    for (int rr = 0; rr < 3; rr++)
        #pragma unroll
        for (int j = 0; j < 8; j++) gaccv[rr][j] = (v2f){ 0.f, 0.f };

    for (int hf = 0; hf < 2; hf++) {
        __syncthreads();                       // EIB/WPan (hf=0) or prior ehTh reads done
        #pragma unroll
        for (int j2 = 0; j2 < 8; j2++) {
            int j = hf * 8 + j2;
            int col = tcol * 4 + (j >> 2) * 32 + (j & 3);
            int lc = col - hf * 64;            // 0..63
            float b = bp[col];
            ehTh[lc * 68 + 2 * trow]     = fmaxf(AIDX(accp0, j) + b, 0.f);
            ehTh[lc * 68 + 2 * trow + 1] = fmaxf(AIDX(accp1, j) + b, 0.f);
        }
        for (int p = 0; p < 4; p++) {
            __syncthreads();                   // ehTh writes visible (p==0) / prior panel reads done
            #pragma unroll
            for (int i = 0; i < 3; i++) {
                int fid = i * 256 + t;         // 0..767 float4s
                int rr = fid >> 8;
                int loc = fid & 255;
                int pr = loc >> 4;             // 0..15
                int pc = (loc & 15) * 4;
                *(float4*)&WgPan[rr * 1024 + pr * 64 + pc] =
                    ld4(&Wg1[(size_t)(rr * 128 + hf * 64 + p * 16 + pr) * 64 + pc]);
            }
            __syncthreads();
            for (int kk = 0; kk < 16; kk++) {
                float4 av = ld4(&ehTh[(p * 16 + kk) * 68 + 4 * gtr]);
                v2f ax = { av.x, av.x }, ay = { av.y, av.y };
                v2f az = { av.z, av.z }, aw = { av.w, av.w };
                #pragma unroll
                for (int rr = 0; rr < 3; rr++) {
                    float4 bv = ld4(&WgPan[rr * 1024 + kk * 64 + 4 * gtc]);
                    v2f bva = { bv.x, bv.y }, bvb = { bv.z, bv.w };
                    gaccv[rr][0] = PKFMA(ax, bva, gaccv[rr][0]);
                    gaccv[rr][1] = PKFMA(ax, bvb, gaccv[rr][1]);
                    gaccv[rr][2] = PKFMA(ay, bva, gaccv[rr][2]);
                    gaccv[rr][3] = PKFMA(ay, bvb, gaccv[rr][3]);
                    gaccv[rr][4] = PKFMA(az, bva, gaccv[rr][4]);
                    gaccv[rr][5] = PKFMA(az, bvb, gaccv[rr][5]);
                    gaccv[rr][6] = PKFMA(aw, bva, gaccv[rr][6]);
                    gaccv[rr][7] = PKFMA(aw, bvb, gaccv[rr][7]);
                }
            }
        }
    }

    // ---- Gbuf + p-phase per regime (R1 lane mapping / add order) ----
    float gc = 0.f;
    for (int rr = 0; rr < 3; rr++) {
        __syncthreads();                       // ehTh k-loop reads (rr==0) / prior p-phase reads done
        #pragma unroll
        for (int j = 0; j < 4; j++) {
            float b = bg1[rr * 64 + 4 * gtc + j];
            float4 g;
            g.x = fmaxf(GIDX(rr, 0  + j) + b, 0.f);
            g.y = fmaxf(GIDX(rr, 4  + j) + b, 0.f);
            g.z = fmaxf(GIDX(rr, 8  + j) + b, 0.f);
            g.w = fmaxf(GIDX(rr, 12 + j) + b, 0.f);
            *(float4*)&Gbuf[(4 * gtc + j) * 68 + 4 * gtr] = g;
        }
        __syncthreads();
        float pacc = 0.f;
        #pragma unroll
        for (int j = 0; j < 16; j++) {
            int m = gq * 4 + (j >> 2) * 16 + (j & 3);
            pacc += Gbuf[m * 68 + grow] * Wg2[rr * 64 + m];
        }
        pacc += __shfl_xor(pacc, 1);
        pacc += __shfl_xor(pacc, 2);
        float gate = 1.f / (1.f + expf(-(pacc + bg2[rr])));
        gc += gate * hdr[1 + rr];
    }
    if (gq == 0) scores[e0 + grow] = rawS[grow] * gc * hdr[4];
}

// ---------------- Kernel D: per-row dedup + softmax + stable top-k ----------------
__global__ __launch_bounds__(64) void finalize_kernel(
    const int* __restrict__ tgt_idx, const float* __restrict__ scores,
    float* __restrict__ out_w, float* __restrict__ out_i)
{
    __shared__ int   tl[32];
    __shared__ float pl[32];
    int j = threadIdx.x;
    int row = blockIdx.x;
    bool lane_active = (j < 32);
    int   tg = 0;
    float s  = -INFINITY;
    if (lane_active) {
        tg = tgt_idx[row * 32 + j];
        s  = scores[row * 32 + j];
        tl[j] = tg;
    }
    __syncthreads();

    bool alive = false;
    if (lane_active) {
        alive = true;
        for (int j2 = j + 1; j2 < 32; j2++)
            if (tl[j2] == tg) { alive = false; break; }
    }
    float z = (lane_active && alive) ? s * (1.f / TEMP) : -INFINITY;
    float m = z;
    #pragma unroll
    for (int mm = 1; mm < 64; mm <<= 1) m = fmaxf(m, __shfl_xor(m, mm));
    float p = (lane_active && alive) ? expf(z - m) : 0.f;
    float sum = p;
    #pragma unroll
    for (int mm = 1; mm < 64; mm <<= 1) sum += __shfl_xor(sum, mm);
    p = p / sum;
    if (lane_active) pl[j] = alive ? p : -1.f;
    __syncthreads();

    int rank = 0, dcount = 0;
    for (int j2 = 0; j2 < 32; j2++) {
        float pj = pl[j2];
        if (pj >= 0.f) {
            dcount++;
            if (lane_active && alive) {
                if (pj > p || (pj == p && tl[j2] < tg)) rank++;
            }
        }
    }
    if (lane_active && alive) {
        out_w[row * 32 + rank] = (p > W_THRESH) ? p : 0.f;
        out_i[row * 32 + rank] = (float)tg;
    }
    if (j == 0) {
        int c = 0;
        for (int slot = dcount; slot < 32; slot++) {
            for (;;) {
                bool found = false;
                for (int q = 0; q < 32; q++) if (tl[q] == c) { found = true; break; }
                if (!found) break;
                c++;
            }
            out_w[row * 32 + slot] = 0.f;
            out_i[row * 32 + slot] = (float)c;
            c++;
        }
    }
}

extern "C" void kernel_launch(void* const* d_in, const int* in_sizes, int n_in,
                              void* d_out, int out_size, void* d_ws, size_t ws_size,
                              hipStream_t stream)
{
    const float* x          = (const float*)d_in[0];
    const int*   edge_index = (const int*)  d_in[1];
    const float* edge_attr  = (const float*)d_in[2];
    const float* Ws1 = (const float*)d_in[3];
    const float* bs1 = (const float*)d_in[4];
    const float* ln_g = (const float*)d_in[5];
    const float* ln_b = (const float*)d_in[6];
    const float* Ws2 = (const float*)d_in[7];
    const float* bs2 = (const float*)d_in[8];
    const float* Wp  = (const float*)d_in[9];
    const float* bp  = (const float*)d_in[10];
    const float* Wr1 = (const float*)d_in[11];
    const float* br1 = (const float*)d_in[12];
    const float* Wr2 = (const float*)d_in[13];
    const float* br2 = (const float*)d_in[14];
    const float* Wg1 = (const float*)d_in[15];
    const float* bg1 = (const float*)d_in[16];
    const float* Wg2 = (const float*)d_in[17];
    const float* bg2 = (const float*)d_in[18];
    const float* Wc1 = (const float*)d_in[19];
    const float* bc1 = (const float*)d_in[20];
    const float* Wc2 = (const float*)d_in[21];
    const float* bc2 = (const float*)d_in[22];

    float* hdr    = (float*)d_ws;
    float* scores = hdr + 128;
    float* tabs   = scores + EE;            // PA1, PA2
    const int* tgt = edge_index + EE;       // row 1 of edge_index

    hipMemsetAsync(d_ws, 0, 512, stream);
    setup_kernel<<<640, 256, 0, stream>>>(x, Ws1, Wp, Wc1, bc1, Wc2, bc2, tabs, hdr);
    regime_kernel<<<1, 128, 0, stream>>>(Wr1, br1, Wr2, br2, hdr);
    edge_fused_kernel<<<EE / 64, 256, 0, stream>>>(
        tgt, edge_attr, x, Ws1, bs1, ln_g, ln_b, Ws2, bs2, Wp, bp,
        Wg1, bg1, Wg2, bg2, tabs, tabs + (size_t)NN * 128, hdr, scores);
    finalize_kernel<<<NN, 64, 0, stream>>>(
        tgt, scores, (float*)d_out, (float*)d_out + NN * KK);
}